// Round 10
// baseline (1059.853 us; speedup 1.0000x reference)
//
#include <hip/hip_runtime.h>
#include <hip/hip_cooperative_groups.h>
#include <hip/hip_bf16.h>

#define N_BUS 200000
#define N_GEN 50000
#define E_BB 1600000
#define E_GB 400000
#define E_BG 400000
#define H 32
#define NBINS 1024   // max coarse buckets (>= ceil(200000/256) = 782)
#define EPT 16       // edges per thread in partition (chunk = 4096)

#define NB_CSR_BUS 782   // ceil(N_BUS/256)
#define NB_CSR_GEN 196   // ceil(N_GEN/256)
#define NB_PART_BB 391   // ceil(E_BB/4096)
#define NB_PART_GB 98
#define NB_PART_BG 98
#define NB_PART_ALL 587
#define NB_TF_BUS 782    // ceil(N_BUS/256)
#define NB_TF_GEN 196
#define NB_TF_ALL 978
#define NB_PL_BUS 6250   // ceil(N_BUS/32)
#define NB_PL_GEN 1563   // ceil(N_GEN/32)
#define LDS_BYTES 36864  // max over phases: tf1 x-tile 256*(64+8)*2

typedef __attribute__((ext_vector_type(8))) short short8;
typedef __attribute__((ext_vector_type(4))) float floatx4;

__device__ inline unsigned short f2bf(float f) {
    __hip_bfloat16 h = __float2bfloat16(f);   // RNE
    return *reinterpret_cast<unsigned short*>(&h);
}
__device__ inline float bf2f(unsigned short u) {
    return __uint_as_float(((unsigned)u) << 16);
}

// ---------------------------------------------------------------------------
// All parameters in one struct (passed by value as the single kernel arg).
struct KParams {
    const int *src_bb, *dst_bb, *src_gb, *dst_gb, *src_bg, *dst_bg;
    const float *x_bus, *x_gen;
    const float *l1_bb_Wl, *l1_bb_bl, *l1_bb_Wr;
    const float *l1_gb_Wl, *l1_gb_bl, *l1_gb_Wr;
    const float *l1_bg_Wl, *l1_bg_bl, *l1_bg_Wr;
    const float *l2_bb_Wl, *l2_bb_bl, *l2_bb_Wr;
    const float *l2_gb_Wl, *l2_gb_bl, *l2_gb_Wr;
    const float *l2_bg_Wl, *l2_bg_bl, *l2_bg_Wr;
    const float *lin0_bus_W, *lin0_bus_b, *linf_bus_W, *linf_bus_b;
    const float *lin0_gen_W, *lin0_gen_b, *linf_gen_W, *linf_gen_b;
    unsigned *rs_bb, *rs_gb, *rs_bg;
    unsigned *cur_bb, *cur_gb, *cur_bg;   // contiguous (cur_bb is base for zeroing)
    unsigned *e_bb, *e_gb, *e_bg;
    unsigned *p_bb, *p_gb, *p_bg;
    unsigned short *y_bb, *y_bg, *y_gb;
    float *h_bus, *h_gen;
    unsigned short *Wf1b, *Wf1g, *Wf2b, *Wf2g;
    float *B1b, *B1g, *B2b, *B2g;
    float *WeB, *beB, *WeG, *beG;
    float *outp;
};

// ---------------------------------------------------------------------------
// Phase bodies (LDS passed in from the mega kernel's single buffer).

__device__ __forceinline__ void prep_body(const KParams& P, int t0, int NT) {
    if (t0 < 3 * NBINS) P.cur_bb[t0] = 0u;   // cursors contiguous

    // L1 bus: KT=2, NTN=6
    for (int f = t0; f < 2 * 6 * 64 * 8; f += NT) {
        int j = f & 7, l = (f >> 3) & 63, tile = f >> 9;
        int nt = tile % 6, kt = tile / 6;
        int k = kt * 32 + (l >> 4) * 8 + j, n = nt * 16 + (l & 15);
        float v;
        if (n < 32) v = P.l1_bb_Wl[k * 32 + n];
        else if (n < 64) v = P.l1_bg_Wl[k * 32 + n - 32];
        else v = P.l1_bb_Wr[k * 32 + n - 64] + P.l1_gb_Wr[k * 32 + n - 64];
        P.Wf1b[f] = f2bf(v);
    }
    // L1 gen: KT=2, NTN=4
    for (int f = t0; f < 2 * 4 * 64 * 8; f += NT) {
        int j = f & 7, l = (f >> 3) & 63, tile = f >> 9;
        int nt = tile % 4, kt = tile / 4;
        int k = kt * 32 + (l >> 4) * 8 + j, n = nt * 16 + (l & 15);
        float v = (n < 32) ? P.l1_gb_Wl[k * 32 + n] : P.l1_bg_Wr[k * 32 + n - 32];
        P.Wf1g[f] = f2bf(v);
    }
    // L2 bus: KT=1, NTN=6
    for (int f = t0; f < 6 * 64 * 8; f += NT) {
        int j = f & 7, l = (f >> 3) & 63, nt = f >> 9;
        int k = (l >> 4) * 8 + j, n = nt * 16 + (l & 15);
        float v;
        if (n < 32) v = P.l2_bb_Wl[k * 32 + n];
        else if (n < 64) v = P.l2_bg_Wl[k * 32 + n - 32];
        else v = P.l2_bb_Wr[k * 32 + n - 64] + P.l2_gb_Wr[k * 32 + n - 64];
        P.Wf2b[f] = f2bf(v);
    }
    // L2 gen: KT=1, NTN=4
    for (int f = t0; f < 4 * 64 * 8; f += NT) {
        int j = f & 7, l = (f >> 3) & 63, nt = f >> 9;
        int k = (l >> 4) * 8 + j, n = nt * 16 + (l & 15);
        float v = (n < 32) ? P.l2_gb_Wl[k * 32 + n] : P.l2_bg_Wr[k * 32 + n - 32];
        P.Wf2g[f] = f2bf(v);
    }
    if (t0 < 96) {
        P.B1b[t0] = (t0 < 64) ? 0.0f : P.l1_bb_bl[t0 - 64] + P.l1_gb_bl[t0 - 64];
        P.B2b[t0] = (t0 < 64) ? 0.0f : P.l2_bb_bl[t0 - 64] + P.l2_gb_bl[t0 - 64];
    }
    if (t0 < 64) {
        P.B1g[t0] = (t0 < 32) ? 0.0f : P.l1_bg_bl[t0 - 32];
        P.B2g[t0] = (t0 < 32) ? 0.0f : P.l2_bg_bl[t0 - 32];
    }
    // Fused head: bus We (32x4) + be(4); gen We (32x2) + be(2)
    if (t0 < 128) {
        int k = t0 >> 2, c = t0 & 3;
        float s = 0.0f;
        for (int m = 0; m < 32; m++) s += P.lin0_bus_W[k * 32 + m] * P.linf_bus_W[m * 4 + c];
        P.WeB[t0] = s;
    }
    if (t0 >= 128 && t0 < 132) {
        int c = t0 - 128;
        float s = P.linf_bus_b[c];
        for (int m = 0; m < 32; m++) s += P.lin0_bus_b[m] * P.linf_bus_W[m * 4 + c];
        P.beB[c] = s;
    }
    if (t0 >= 132 && t0 < 196) {
        int i = t0 - 132, k = i >> 1, c = i & 1;
        float s = 0.0f;
        for (int m = 0; m < 32; m++) s += P.lin0_gen_W[k * 32 + m] * P.linf_gen_W[m * 2 + c];
        P.WeG[i] = s;
    }
    if (t0 >= 196 && t0 < 198) {
        int c = t0 - 196;
        float s = P.linf_gen_b[c];
        for (int m = 0; m < 32; m++) s += P.lin0_gen_b[m] * P.linf_gen_W[m * 2 + c];
        P.beG[c] = s;
    }
}

__device__ __forceinline__ void hist_body(int blk, int nb, const int* __restrict__ dst,
                                          int nE, unsigned* __restrict__ bcnt, unsigned* h) {
    for (int i = threadIdx.x; i < NBINS; i += 256) h[i] = 0;
    __syncthreads();
    for (int e = blk * 256 + threadIdx.x; e < nE; e += nb * 256)
        atomicAdd(&h[(unsigned)dst[e] >> 8], 1u);
    __syncthreads();
    for (int i = threadIdx.x; i < NBINS; i += 256)
        if (h[i]) atomicAdd(&bcnt[i], h[i]);
}

__device__ __forceinline__ void scan_body(unsigned* __restrict__ a, unsigned* sh) {
    int tid = threadIdx.x;
    int base = tid * 4;
    unsigned v[4], ts = 0;
#pragma unroll
    for (int q = 0; q < 4; q++) { v[q] = a[base + q]; ts += v[q]; }
    sh[tid] = ts;
    __syncthreads();
#pragma unroll
    for (int d = 1; d < 256; d <<= 1) {
        unsigned t = (tid >= d) ? sh[tid - d] : 0u;
        __syncthreads();
        sh[tid] += t;
        __syncthreads();
    }
    unsigned run = sh[tid] - ts;
#pragma unroll
    for (int q = 0; q < 4; q++) { a[base + q] = run; run += v[q]; }
}

__device__ __forceinline__ void part_body(int blk, const int* __restrict__ src,
                                          const int* __restrict__ dst, int nE,
                                          unsigned* __restrict__ cursor,
                                          unsigned* __restrict__ pairs,
                                          unsigned* hist, unsigned* base) {
    const int tid = threadIdx.x;
    const int cbase = blk * (256 * EPT);

    unsigned es[EPT], ed[EPT];
#pragma unroll
    for (int q = 0; q < EPT; q++) {
        int i = cbase + q * 256 + tid;
        if (i < nE) { es[q] = (unsigned)src[i]; ed[q] = (unsigned)dst[i]; }
        else ed[q] = 0xFFFFFFFFu;
    }
    for (int i = tid; i < NBINS; i += 256) hist[i] = 0;
    __syncthreads();
#pragma unroll
    for (int q = 0; q < EPT; q++)
        if (ed[q] != 0xFFFFFFFFu) atomicAdd(&hist[ed[q] >> 8], 1u);
    __syncthreads();
    for (int i = tid; i < NBINS; i += 256) {
        unsigned c = hist[i];
        base[i] = c ? atomicAdd(&cursor[i], c) : 0u;
        hist[i] = 0;  // reuse as local cursor
    }
    __syncthreads();
#pragma unroll
    for (int q = 0; q < EPT; q++) {
        if (ed[q] != 0xFFFFFFFFu) {
            unsigned b = ed[q] >> 8;
            unsigned off = atomicAdd(&hist[b], 1u);
            pairs[base[b] + off] = ((ed[q] & 255u) << 24) | es[q];
        }
    }
}

__device__ __forceinline__ void fine_body(int b, const unsigned* __restrict__ cursor,
                                          const unsigned* __restrict__ pairs,
                                          unsigned* __restrict__ rs,
                                          unsigned* __restrict__ esrc, int nDst,
                                          unsigned* cnt, unsigned* sh) {
    const int tid = threadIdx.x;
    const unsigned start = b ? cursor[b - 1] : 0u;
    const unsigned end = cursor[b];

    cnt[tid] = 0;
    __syncthreads();
    for (unsigned k = start + tid; k < end; k += 256)
        atomicAdd(&cnt[pairs[k] >> 24], 1u);
    __syncthreads();
    unsigned c = cnt[tid];
    sh[tid] = c;
    __syncthreads();
#pragma unroll
    for (int d = 1; d < 256; d <<= 1) {
        unsigned t = (tid >= d) ? sh[tid - d] : 0u;
        __syncthreads();
        sh[tid] += t;
        __syncthreads();
    }
    int gd = b * 256 + tid;
    if (gd < nDst) rs[gd] = start + sh[tid];  // inclusive row end
    cnt[tid] = sh[tid] - c;                   // exclusive offset -> cursor
    __syncthreads();
    for (unsigned k = start + tid; k < end; k += 256) {
        unsigned p = pairs[k];
        unsigned off = atomicAdd(&cnt[p >> 24], 1u);
        esrc[start + off] = p & 0x00FFFFFFu;
    }
}

// bf16 MFMA GEMM [256 x K] @ [K x NOUT] per virtual block.
template <int K, int NOUT, bool RELU_IN>
__device__ __forceinline__ void transform_body(
    int blk, const float* x, int n,
    const unsigned short* __restrict__ Wf, const float* __restrict__ bias,
    unsigned short* __restrict__ y0, unsigned short* __restrict__ y1, float* h,
    char* ldsraw)
{
    constexpr int KT = K / 32, NTN = NOUT / 16, NCH = NOUT / 32;
    constexpr int XS = K + 8;  // shorts
    constexpr int OS = 34;     // floats
    short* lx = (short*)ldsraw;
    float* lo = (float*)ldsraw;

    const int tid = threadIdx.x;
    const int base = blk * 256;
    const int rows = min(256, n - base);
    const int w = tid >> 6, l = tid & 63, quad = l >> 4, ln = l & 15;

    // B fragments + bias
    short8 bf[KT][NTN];
    const short8* wf8 = (const short8*)Wf;
#pragma unroll
    for (int kt = 0; kt < KT; kt++)
#pragma unroll
        for (int nt = 0; nt < NTN; nt++)
            bf[kt][nt] = wf8[(kt * NTN + nt) * 64 + l];
    float bv[NTN];
#pragma unroll
    for (int nt = 0; nt < NTN; nt++) bv[nt] = bias[nt * 16 + ln];

    // ---- stage x tile (fp32 -> bf16, optional relu) ----
    {
        const float4* xg = (const float4*)(x + (size_t)base * K);
        const int T4 = rows * (K / 4);
        for (int q = tid; q < T4; q += 256) {
            float4 v = xg[q];
            if (RELU_IN) {
                v.x = fmaxf(v.x, 0.f); v.y = fmaxf(v.y, 0.f);
                v.z = fmaxf(v.z, 0.f); v.w = fmaxf(v.w, 0.f);
            }
            int r = q / (K / 4), c = (q % (K / 4)) * 4;
            short4 s4;
            s4.x = (short)f2bf(v.x); s4.y = (short)f2bf(v.y);
            s4.z = (short)f2bf(v.z); s4.w = (short)f2bf(v.w);
            *(short4*)&lx[r * XS + c] = s4;
        }
    }
    __syncthreads();

    // ---- MFMA: wave w owns rows [w*64, w*64+64) ----
    floatx4 acc[4][NTN];
#pragma unroll
    for (int mt = 0; mt < 4; mt++)
#pragma unroll
        for (int nt = 0; nt < NTN; nt++) {
            floatx4 c0 = {bv[nt], bv[nt], bv[nt], bv[nt]};
            acc[mt][nt] = c0;
        }
#pragma unroll
    for (int mt = 0; mt < 4; mt++) {
        const int row = w * 64 + mt * 16 + ln;  // A[m = lane&15][k = quad*8+j]
#pragma unroll
        for (int kt = 0; kt < KT; kt++) {
            short8 af = *(const short8*)&lx[row * XS + kt * 32 + quad * 8];
#pragma unroll
            for (int nt = 0; nt < NTN; nt++)
                acc[mt][nt] = __builtin_amdgcn_mfma_f32_16x16x32_bf16(
                    af, bf[kt][nt], acc[mt][nt], 0, 0, 0);
        }
    }

    // ---- epilogue: per-32-col chunk LDS transpose -> coalesced stores ----
    // C/D layout: col = lane&15, row = quad*4 + reg.
#pragma unroll
    for (int c = 0; c < NCH; c++) {
        __syncthreads();
#pragma unroll
        for (int mt = 0; mt < 4; mt++)
#pragma unroll
            for (int d = 0; d < 2; d++) {
                int nt = 2 * c + d;
#pragma unroll
                for (int r = 0; r < 4; r++)
                    lo[(w * 64 + mt * 16 + quad * 4 + r) * OS + d * 16 + ln] = acc[mt][nt][r];
            }
        __syncthreads();
        const int T4 = rows * 8;
        if (c == NCH - 1) {  // h chunk, fp32
            float* og = h + (size_t)base * 32;
            for (int q = tid; q < T4; q += 256) {
                int r = q >> 3, cc = (q & 7) * 4;
                const float* p = &lo[r * OS + cc];
                *(float4*)(og + q * 4) = make_float4(p[0], p[1], p[2], p[3]);
            }
        } else {  // y chunk, bf16
            unsigned short* og = ((c == 0) ? y0 : y1) + (size_t)base * 32;
            for (int q = tid; q < T4; q += 256) {
                int r = q >> 3, cc = (q & 7) * 4;
                const float* p = &lo[r * OS + cc];
                short4 s4;
                s4.x = (short)f2bf(p[0]); s4.y = (short)f2bf(p[1]);
                s4.z = (short)f2bf(p[2]); s4.w = (short)f2bf(p[3]);
                *(short4*)(og + q * 4) = s4;
            }
        }
    }
}

// Pull (bf16 y), 4-way pipelined gathers; 8 threads/node.
// FUSE: relu + fused head (We 32xD, be D), write out directly.
template <bool FUSE>
__device__ __forceinline__ void pull_body(
    int blk, bool hasB, int n,
    const unsigned* __restrict__ rsA, const unsigned* __restrict__ eA, const unsigned short* __restrict__ yA,
    const unsigned* __restrict__ rsB, const unsigned* __restrict__ eB, const unsigned short* __restrict__ yB,
    float* __restrict__ h,
    const float* __restrict__ We, const float* __restrict__ be, int DOUT, float* __restrict__ outp)
{
    const int tid = threadIdx.x;
    unsigned node = blk * 32u + (tid >> 3);
    int j = (tid & 7) * 4;
    if (node >= (unsigned)n) return;

    float4 r = *(const float4*)(h + (size_t)node * H + j);  // root term

    auto accum_rel = [&](const unsigned* __restrict__ rs, const unsigned* __restrict__ e,
                         const unsigned short* __restrict__ y) {
        unsigned k0 = node ? rs[node - 1] : 0u;
        unsigned k1 = rs[node];
        float4 a0 = make_float4(0.f, 0.f, 0.f, 0.f);
        float4 a1 = make_float4(0.f, 0.f, 0.f, 0.f);
        float4 a2 = make_float4(0.f, 0.f, 0.f, 0.f);
        float4 a3 = make_float4(0.f, 0.f, 0.f, 0.f);
        unsigned k = k0;
        for (; k + 4 <= k1; k += 4) {
            unsigned s0 = e[k], s1 = e[k + 1], s2 = e[k + 2], s3 = e[k + 3];
            ushort4 v0 = *(const ushort4*)(y + (size_t)s0 * H + j);
            ushort4 v1 = *(const ushort4*)(y + (size_t)s1 * H + j);
            ushort4 v2 = *(const ushort4*)(y + (size_t)s2 * H + j);
            ushort4 v3 = *(const ushort4*)(y + (size_t)s3 * H + j);
            a0.x += bf2f(v0.x); a0.y += bf2f(v0.y); a0.z += bf2f(v0.z); a0.w += bf2f(v0.w);
            a1.x += bf2f(v1.x); a1.y += bf2f(v1.y); a1.z += bf2f(v1.z); a1.w += bf2f(v1.w);
            a2.x += bf2f(v2.x); a2.y += bf2f(v2.y); a2.z += bf2f(v2.z); a2.w += bf2f(v2.w);
            a3.x += bf2f(v3.x); a3.y += bf2f(v3.y); a3.z += bf2f(v3.z); a3.w += bf2f(v3.w);
        }
        for (; k < k1; ++k) {
            unsigned s = e[k];
            const ushort4 v = *(const ushort4*)(y + (size_t)s * H + j);
            a0.x += bf2f(v.x); a0.y += bf2f(v.y); a0.z += bf2f(v.z); a0.w += bf2f(v.w);
        }
        a0.x += a1.x + a2.x + a3.x; a0.y += a1.y + a2.y + a3.y;
        a0.z += a1.z + a2.z + a3.z; a0.w += a1.w + a2.w + a3.w;
        unsigned c = k1 - k0;
        float inv = 1.0f / (float)(c > 1u ? c : 1u);
        r.x += a0.x * inv; r.y += a0.y * inv; r.z += a0.z * inv; r.w += a0.w * inv;
    };

    accum_rel(rsA, eA, yA);
    if (hasB) accum_rel(rsB, eB, yB);

    if (!FUSE) {
        *(float4*)(h + (size_t)node * H + j) = r;
        return;
    }

    float p0 = fmaxf(r.x, 0.f), p1 = fmaxf(r.y, 0.f), p2 = fmaxf(r.z, 0.f), p3 = fmaxf(r.w, 0.f);
    float tot[4];
#pragma unroll
    for (int c = 0; c < 4; c++) {
        if (c < DOUT) {
            tot[c] = p0 * We[(j + 0) * DOUT + c] + p1 * We[(j + 1) * DOUT + c]
                   + p2 * We[(j + 2) * DOUT + c] + p3 * We[(j + 3) * DOUT + c];
        } else tot[c] = 0.f;
    }
#pragma unroll
    for (int mask = 1; mask <= 4; mask <<= 1) {
#pragma unroll
        for (int c = 0; c < 4; c++) tot[c] += __shfl_xor(tot[c], mask);
    }
    if ((tid & 7) == 0) {
        if (DOUT == 4) {
            *(float4*)(outp + (size_t)node * 4) =
                make_float4(tot[0] + be[0], tot[1] + be[1], tot[2] + be[2], tot[3] + be[3]);
        } else {
            *(float2*)(outp + (size_t)node * 2) = make_float2(tot[0] + be[0], tot[1] + be[1]);
        }
    }
}

// ---------------------------------------------------------------------------
// Cooperative mega-kernel: all 9 phases, grid.sync() between (strictly serial
// -- R9 lesson: never co-schedule scattered-write and streaming-write phases).
__global__ __launch_bounds__(256, 4) void mega_kernel(KParams P) {
    __shared__ __align__(16) char lds[LDS_BYTES];
    cooperative_groups::grid_group gg = cooperative_groups::this_grid();
    const int G = gridDim.x;
    const int bx = blockIdx.x;

    // P0: weight prep + head folding + cursor zeroing
    prep_body(P, bx * 256 + threadIdx.x, G * 256);
    gg.sync();

    // P1: coarse histogram
    for (int vb = bx; vb < 448; vb += G) {
        __syncthreads();
        if (vb < 256) hist_body(vb, 256, P.dst_bb, E_BB, P.cur_bb, (unsigned*)lds);
        else if (vb < 352) hist_body(vb - 256, 96, P.dst_gb, E_GB, P.cur_gb, (unsigned*)lds);
        else hist_body(vb - 352, 96, P.dst_bg, E_BG, P.cur_bg, (unsigned*)lds);
    }
    gg.sync();

    // P2: exclusive scans (3 items)
    for (int vb = bx; vb < 3; vb += G) {
        __syncthreads();
        scan_body(vb == 0 ? P.cur_bb : (vb == 1 ? P.cur_gb : P.cur_bg), (unsigned*)lds);
    }
    gg.sync();

    // P3: partition (scattered pair writes -- runs alone)
    for (int vb = bx; vb < NB_PART_ALL; vb += G) {
        __syncthreads();
        unsigned* hist = (unsigned*)lds;
        unsigned* basep = hist + NBINS;
        if (vb < NB_PART_BB) part_body(vb, P.src_bb, P.dst_bb, E_BB, P.cur_bb, P.p_bb, hist, basep);
        else if (vb < NB_PART_BB + NB_PART_GB) part_body(vb - NB_PART_BB, P.src_gb, P.dst_gb, E_GB, P.cur_gb, P.p_gb, hist, basep);
        else part_body(vb - NB_PART_BB - NB_PART_GB, P.src_bg, P.dst_bg, E_BG, P.cur_bg, P.p_bg, hist, basep);
    }
    gg.sync();

    // P4: fine CSR
    for (int vb = bx; vb < 2 * NB_CSR_BUS + NB_CSR_GEN; vb += G) {
        __syncthreads();
        unsigned* cnt = (unsigned*)lds;
        unsigned* sh = cnt + 256;
        if (vb < NB_CSR_BUS) fine_body(vb, P.cur_bb, P.p_bb, P.rs_bb, P.e_bb, N_BUS, cnt, sh);
        else if (vb < 2 * NB_CSR_BUS) fine_body(vb - NB_CSR_BUS, P.cur_gb, P.p_gb, P.rs_gb, P.e_gb, N_BUS, cnt, sh);
        else fine_body(vb - 2 * NB_CSR_BUS, P.cur_bg, P.p_bg, P.rs_bg, P.e_bg, N_GEN, cnt, sh);
    }
    gg.sync();

    // P5: layer-1 transforms
    for (int vb = bx; vb < NB_TF_ALL; vb += G) {
        __syncthreads();
        if (vb < NB_TF_BUS)
            transform_body<64, 96, false>(vb, P.x_bus, N_BUS, P.Wf1b, P.B1b, P.y_bb, P.y_bg, P.h_bus, lds);
        else
            transform_body<64, 64, false>(vb - NB_TF_BUS, P.x_gen, N_GEN, P.Wf1g, P.B1g, P.y_gb, nullptr, P.h_gen, lds);
    }
    gg.sync();

    // P6: layer-1 pull
    for (int vb = bx; vb < NB_PL_BUS + NB_PL_GEN; vb += G) {
        if (vb < NB_PL_BUS)
            pull_body<false>(vb, true, N_BUS, P.rs_bb, P.e_bb, P.y_bb, P.rs_gb, P.e_gb, P.y_gb,
                             P.h_bus, P.WeB, P.beB, 4, nullptr);
        else
            pull_body<false>(vb - NB_PL_BUS, false, N_GEN, P.rs_bg, P.e_bg, P.y_bg,
                             nullptr, nullptr, nullptr, P.h_gen, P.WeG, P.beG, 2, nullptr);
    }
    gg.sync();

    // P7: layer-2 transforms (relu on staging; h in-place)
    for (int vb = bx; vb < NB_TF_ALL; vb += G) {
        __syncthreads();
        if (vb < NB_TF_BUS)
            transform_body<32, 96, true>(vb, P.h_bus, N_BUS, P.Wf2b, P.B2b, P.y_bb, P.y_bg, P.h_bus, lds);
        else
            transform_body<32, 64, true>(vb - NB_TF_BUS, P.h_gen, N_GEN, P.Wf2g, P.B2g, P.y_gb, nullptr, P.h_gen, lds);
    }
    gg.sync();

    // P8: layer-2 pull + fused head -> d_out
    for (int vb = bx; vb < NB_PL_BUS + NB_PL_GEN; vb += G) {
        if (vb < NB_PL_BUS)
            pull_body<true>(vb, true, N_BUS, P.rs_bb, P.e_bb, P.y_bb, P.rs_gb, P.e_gb, P.y_gb,
                            P.h_bus, P.WeB, P.beB, 4, P.outp);
        else
            pull_body<true>(vb - NB_PL_BUS, false, N_GEN, P.rs_bg, P.e_bg, P.y_bg,
                            nullptr, nullptr, nullptr, P.h_gen, P.WeG, P.beG, 2,
                            P.outp + (size_t)N_BUS * 4);
    }
}

// ---------------------------------------------------------------------------
extern "C" void kernel_launch(void* const* d_in, const int* in_sizes, int n_in,
                              void* d_out, int out_size, void* d_ws, size_t ws_size,
                              hipStream_t stream) {
    KParams P;
    P.x_bus = (const float*)d_in[0];
    P.x_gen = (const float*)d_in[1];
    P.src_bb = (const int*)d_in[2];
    P.dst_bb = (const int*)d_in[3];
    P.src_gb = (const int*)d_in[4];
    P.dst_gb = (const int*)d_in[5];
    P.src_bg = (const int*)d_in[6];
    P.dst_bg = (const int*)d_in[7];
    P.l1_bb_Wl = (const float*)d_in[8];
    P.l1_bb_bl = (const float*)d_in[9];
    P.l1_bb_Wr = (const float*)d_in[10];
    P.l1_gb_Wl = (const float*)d_in[11];
    P.l1_gb_bl = (const float*)d_in[12];
    P.l1_gb_Wr = (const float*)d_in[13];
    P.l1_bg_Wl = (const float*)d_in[14];
    P.l1_bg_bl = (const float*)d_in[15];
    P.l1_bg_Wr = (const float*)d_in[16];
    P.l2_bb_Wl = (const float*)d_in[17];
    P.l2_bb_bl = (const float*)d_in[18];
    P.l2_bb_Wr = (const float*)d_in[19];
    P.l2_gb_Wl = (const float*)d_in[20];
    P.l2_gb_bl = (const float*)d_in[21];
    P.l2_gb_Wr = (const float*)d_in[22];
    P.l2_bg_Wl = (const float*)d_in[23];
    P.l2_bg_bl = (const float*)d_in[24];
    P.l2_bg_Wr = (const float*)d_in[25];
    P.lin0_bus_W = (const float*)d_in[26];
    P.lin0_bus_b = (const float*)d_in[27];
    P.linf_bus_W = (const float*)d_in[28];
    P.linf_bus_b = (const float*)d_in[29];
    P.lin0_gen_W = (const float*)d_in[30];
    P.lin0_gen_b = (const float*)d_in[31];
    P.linf_gen_W = (const float*)d_in[32];
    P.linf_gen_b = (const float*)d_in[33];
    P.outp = (float*)d_out;

    // Workspace layout (~95 MB).
    char* ws = (char*)d_ws;
    size_t off = 0;
    auto alloc = [&](size_t bytes) {
        char* p = ws + off;
        off += (bytes + 255) & ~(size_t)255;
        return p;
    };
    P.rs_bb = (unsigned*)alloc((size_t)N_BUS * 4);
    P.rs_gb = (unsigned*)alloc((size_t)N_BUS * 4);
    P.rs_bg = (unsigned*)alloc((size_t)N_GEN * 4);
    P.cur_bb = (unsigned*)alloc(NBINS * 4);   // these three must stay contiguous
    P.cur_gb = (unsigned*)alloc(NBINS * 4);
    P.cur_bg = (unsigned*)alloc(NBINS * 4);
    P.e_bb = (unsigned*)alloc((size_t)E_BB * 4);
    P.e_gb = (unsigned*)alloc((size_t)E_GB * 4);
    P.e_bg = (unsigned*)alloc((size_t)E_BG * 4);
    P.p_bb = (unsigned*)alloc((size_t)E_BB * 4);
    P.p_gb = (unsigned*)alloc((size_t)E_GB * 4);
    P.p_bg = (unsigned*)alloc((size_t)E_BG * 4);
    P.y_bb = (unsigned short*)alloc((size_t)N_BUS * H * 2);
    P.y_bg = (unsigned short*)alloc((size_t)N_BUS * H * 2);
    P.y_gb = (unsigned short*)alloc((size_t)N_GEN * H * 2);
    P.h_bus = (float*)alloc((size_t)N_BUS * H * 4);
    P.h_gen = (float*)alloc((size_t)N_GEN * H * 4);
    P.Wf1b = (unsigned short*)alloc(2 * 6 * 64 * 8 * 2);
    P.B1b = (float*)alloc(96 * 4);
    P.Wf1g = (unsigned short*)alloc(2 * 4 * 64 * 8 * 2);
    P.B1g = (float*)alloc(64 * 4);
    P.Wf2b = (unsigned short*)alloc(6 * 64 * 8 * 2);
    P.B2b = (float*)alloc(96 * 4);
    P.Wf2g = (unsigned short*)alloc(4 * 64 * 8 * 2);
    P.B2g = (float*)alloc(64 * 4);
    P.WeB = (float*)alloc(128 * 4);
    P.beB = (float*)alloc(4 * 4);
    P.WeG = (float*)alloc(64 * 4);
    P.beG = (float*)alloc(2 * 4);

    // Cooperative grid: max co-resident blocks (expect 4/CU from 36 KB LDS).
    int dev = 0;
    hipGetDevice(&dev);
    hipDeviceProp_t prop;
    hipGetDeviceProperties(&prop, dev);
    int nbPerCU = 0;
    hipError_t oe = hipOccupancyMaxActiveBlocksPerMultiprocessor(&nbPerCU, mega_kernel, 256, 0);
    if (oe != hipSuccess || nbPerCU < 1) nbPerCU = 1;
    int grid = nbPerCU * prop.multiProcessorCount;

    void* kargs[] = { (void*)&P };
    hipLaunchCooperativeKernel((void*)mega_kernel, dim3(grid), dim3(256), kargs, 0, stream);
}

// Round 11
// 351.948 us; speedup vs baseline: 3.0114x; 3.0114x over previous
//
#include <hip/hip_runtime.h>
#include <hip/hip_bf16.h>

#define N_BUS 200000
#define N_GEN 50000
#define E_BB 1600000
#define E_GB 400000
#define E_BG 400000
#define H 32
#define NBINS 1024   // max coarse buckets (>= ceil(200000/256) = 782)
#define EPT 16       // edges per thread in partition (chunk = 4096)

#define NBK_BUS 782      // buckets for bus-dst relations
#define NBK_GEN 196      // buckets for gen-dst relations
#define CAP_BB 2560      // mean 2046 + >11 sigma
#define CAP_GB 768       // mean 512  + >11 sigma
#define CAP_BG 2560      // mean 2041 + >11 sigma

#define NB_PART_BB 391   // ceil(E_BB/4096)
#define NB_PART_GB 98
#define NB_PART_BG 98
#define NB_PART_ALL 587
#define NB_TF_BUS 782
#define NB_TF_GEN 196
#define NB_PL_BUS 6250   // ceil(N_BUS/32)
#define NB_PL_GEN 1563

typedef __attribute__((ext_vector_type(8))) short short8;
typedef __attribute__((ext_vector_type(4))) float floatx4;

__device__ inline unsigned short f2bf(float f) {
    __hip_bfloat16 h = __float2bfloat16(f);   // RNE
    return *reinterpret_cast<unsigned short*>(&h);
}
__device__ inline float bf2f(unsigned short u) {
    return __uint_as_float(((unsigned)u) << 16);
}

// ---------------------------------------------------------------------------
// Partition into fixed-capacity buckets: block-staged chunk, ONE global
// atomic per (block,bucket); pairs[b*CAP + off] = (dst&255)<<24 | src.
// No histogram or scan needed (CAP > max bucket count by >10 sigma).
__device__ __forceinline__ void part_body(int blk, const int* __restrict__ src,
                                          const int* __restrict__ dst, int nE,
                                          unsigned* __restrict__ cnt, int CAP,
                                          unsigned* __restrict__ pairs) {
    __shared__ unsigned hist[NBINS];
    __shared__ unsigned base[NBINS];
    const int tid = threadIdx.x;
    const int cbase = blk * (256 * EPT);

    unsigned es[EPT], ed[EPT];
#pragma unroll
    for (int q = 0; q < EPT; q++) {
        int i = cbase + q * 256 + tid;
        if (i < nE) { es[q] = (unsigned)src[i]; ed[q] = (unsigned)dst[i]; }
        else ed[q] = 0xFFFFFFFFu;
    }
    for (int i = tid; i < NBINS; i += 256) hist[i] = 0;
    __syncthreads();
#pragma unroll
    for (int q = 0; q < EPT; q++)
        if (ed[q] != 0xFFFFFFFFu) atomicAdd(&hist[ed[q] >> 8], 1u);
    __syncthreads();
    for (int i = tid; i < NBINS; i += 256) {
        unsigned c = hist[i];
        base[i] = c ? ((unsigned)i * CAP + atomicAdd(&cnt[i], c)) : 0u;
        hist[i] = 0;  // reuse as local cursor
    }
    __syncthreads();
#pragma unroll
    for (int q = 0; q < EPT; q++) {
        if (ed[q] != 0xFFFFFFFFu) {
            unsigned b = ed[q] >> 8;
            unsigned off = atomicAdd(&hist[b], 1u);
            pairs[base[b] + off] = ((ed[q] & 255u) << 24) | es[q];
        }
    }
}

__global__ __launch_bounds__(256) void part_all_kernel(
    const int* __restrict__ sbb, const int* __restrict__ dbb, unsigned* __restrict__ cbb, unsigned* __restrict__ pbb,
    const int* __restrict__ sgb, const int* __restrict__ dgb, unsigned* __restrict__ cgb, unsigned* __restrict__ pgb,
    const int* __restrict__ sbg, const int* __restrict__ dbg, unsigned* __restrict__ cbg, unsigned* __restrict__ pbg)
{
    int b = blockIdx.x;
    if (b < NB_PART_BB) part_body(b, sbb, dbb, E_BB, cbb, CAP_BB, pbb);
    else if (b < NB_PART_BB + NB_PART_GB) part_body(b - NB_PART_BB, sgb, dgb, E_GB, cgb, CAP_GB, pgb);
    else part_body(b - NB_PART_BB - NB_PART_GB, sbg, dbg, E_BG, cbg, CAP_BG, pbg);
}

// ---------------------------------------------------------------------------
// Fine CSR: one block per bucket. Region [b*CAP, b*CAP + cnt[b]).
// rs[node] packed: (global row start << 9) | degree  (start < 2^21, deg < 512).
__device__ __forceinline__ void fine_body(int b, const unsigned* __restrict__ cnt_g, int CAP,
                                          const unsigned* __restrict__ pairs,
                                          unsigned* __restrict__ rs,
                                          unsigned* __restrict__ esrc, int nDst) {
    __shared__ unsigned cnt[256];
    __shared__ unsigned sh[256];
    const int tid = threadIdx.x;
    const unsigned start = (unsigned)b * CAP;
    const unsigned end = start + cnt_g[b];

    cnt[tid] = 0;
    __syncthreads();
    for (unsigned k = start + tid; k < end; k += 256)
        atomicAdd(&cnt[pairs[k] >> 24], 1u);
    __syncthreads();
    unsigned c = cnt[tid];
    sh[tid] = c;
    __syncthreads();
#pragma unroll
    for (int d = 1; d < 256; d <<= 1) {
        unsigned t = (tid >= d) ? sh[tid - d] : 0u;
        __syncthreads();
        sh[tid] += t;
        __syncthreads();
    }
    int gd = b * 256 + tid;
    unsigned rowstart = start + sh[tid] - c;
    if (gd < nDst) rs[gd] = (rowstart << 9) | (c < 511u ? c : 511u);
    cnt[tid] = sh[tid] - c;  // exclusive offset -> cursor
    __syncthreads();
    for (unsigned k = start + tid; k < end; k += 256) {
        unsigned p = pairs[k];
        unsigned off = atomicAdd(&cnt[p >> 24], 1u);
        esrc[start + off] = p & 0x00FFFFFFu;
    }
}

__global__ __launch_bounds__(256) void fine_all_kernel(
    const unsigned* __restrict__ cbb, const unsigned* __restrict__ pbb, unsigned* __restrict__ rsbb, unsigned* __restrict__ ebb,
    const unsigned* __restrict__ cgb, const unsigned* __restrict__ pgb, unsigned* __restrict__ rsgb, unsigned* __restrict__ egb,
    const unsigned* __restrict__ cbg, const unsigned* __restrict__ pbg, unsigned* __restrict__ rsbg, unsigned* __restrict__ ebg)
{
    int b = blockIdx.x;
    if (b < NBK_BUS) fine_body(b, cbb, CAP_BB, pbb, rsbb, ebb, N_BUS);
    else if (b < 2 * NBK_BUS) fine_body(b - NBK_BUS, cgb, CAP_GB, pgb, rsgb, egb, N_BUS);
    else fine_body(b - 2 * NBK_BUS, cbg, CAP_BG, pbg, rsbg, ebg, N_GEN);
}

// ---------------------------------------------------------------------------
// Prep: bf16 MFMA B-fragments + fused biases + fused head matrices + zero
// the 3*NBINS bucket counters.
__global__ __launch_bounds__(256) void prep_kernel(
    const float* __restrict__ l1_bb_Wl, const float* __restrict__ l1_bb_bl, const float* __restrict__ l1_bb_Wr,
    const float* __restrict__ l1_gb_Wl, const float* __restrict__ l1_gb_bl, const float* __restrict__ l1_gb_Wr,
    const float* __restrict__ l1_bg_Wl, const float* __restrict__ l1_bg_bl, const float* __restrict__ l1_bg_Wr,
    const float* __restrict__ l2_bb_Wl, const float* __restrict__ l2_bb_bl, const float* __restrict__ l2_bb_Wr,
    const float* __restrict__ l2_gb_Wl, const float* __restrict__ l2_gb_bl, const float* __restrict__ l2_gb_Wr,
    const float* __restrict__ l2_bg_Wl, const float* __restrict__ l2_bg_bl, const float* __restrict__ l2_bg_Wr,
    const float* __restrict__ lin0_bus_W, const float* __restrict__ lin0_bus_b,
    const float* __restrict__ linf_bus_W, const float* __restrict__ linf_bus_b,
    const float* __restrict__ lin0_gen_W, const float* __restrict__ lin0_gen_b,
    const float* __restrict__ linf_gen_W, const float* __restrict__ linf_gen_b,
    unsigned short* __restrict__ Wf1b, float* __restrict__ B1b,
    unsigned short* __restrict__ Wf1g, float* __restrict__ B1g,
    unsigned short* __restrict__ Wf2b, float* __restrict__ B2b,
    unsigned short* __restrict__ Wf2g, float* __restrict__ B2g,
    float* __restrict__ WeB, float* __restrict__ beB,
    float* __restrict__ WeG, float* __restrict__ beG,
    unsigned* __restrict__ cursors)
{
    int t0 = blockIdx.x * 256 + threadIdx.x;
    int NT = gridDim.x * 256;

    if (t0 < 3 * NBINS) cursors[t0] = 0u;

    // L1 bus: KT=2, NTN=6
    for (int f = t0; f < 2 * 6 * 64 * 8; f += NT) {
        int j = f & 7, l = (f >> 3) & 63, tile = f >> 9;
        int nt = tile % 6, kt = tile / 6;
        int k = kt * 32 + (l >> 4) * 8 + j, n = nt * 16 + (l & 15);
        float v;
        if (n < 32) v = l1_bb_Wl[k * 32 + n];
        else if (n < 64) v = l1_bg_Wl[k * 32 + n - 32];
        else v = l1_bb_Wr[k * 32 + n - 64] + l1_gb_Wr[k * 32 + n - 64];
        Wf1b[f] = f2bf(v);
    }
    // L1 gen: KT=2, NTN=4
    for (int f = t0; f < 2 * 4 * 64 * 8; f += NT) {
        int j = f & 7, l = (f >> 3) & 63, tile = f >> 9;
        int nt = tile % 4, kt = tile / 4;
        int k = kt * 32 + (l >> 4) * 8 + j, n = nt * 16 + (l & 15);
        float v = (n < 32) ? l1_gb_Wl[k * 32 + n] : l1_bg_Wr[k * 32 + n - 32];
        Wf1g[f] = f2bf(v);
    }
    // L2 bus: KT=1, NTN=6
    for (int f = t0; f < 6 * 64 * 8; f += NT) {
        int j = f & 7, l = (f >> 3) & 63, nt = f >> 9;
        int k = (l >> 4) * 8 + j, n = nt * 16 + (l & 15);
        float v;
        if (n < 32) v = l2_bb_Wl[k * 32 + n];
        else if (n < 64) v = l2_bg_Wl[k * 32 + n - 32];
        else v = l2_bb_Wr[k * 32 + n - 64] + l2_gb_Wr[k * 32 + n - 64];
        Wf2b[f] = f2bf(v);
    }
    // L2 gen: KT=1, NTN=4
    for (int f = t0; f < 4 * 64 * 8; f += NT) {
        int j = f & 7, l = (f >> 3) & 63, nt = f >> 9;
        int k = (l >> 4) * 8 + j, n = nt * 16 + (l & 15);
        float v = (n < 32) ? l2_gb_Wl[k * 32 + n] : l2_bg_Wr[k * 32 + n - 32];
        Wf2g[f] = f2bf(v);
    }
    if (t0 < 96) {
        B1b[t0] = (t0 < 64) ? 0.0f : l1_bb_bl[t0 - 64] + l1_gb_bl[t0 - 64];
        B2b[t0] = (t0 < 64) ? 0.0f : l2_bb_bl[t0 - 64] + l2_gb_bl[t0 - 64];
    }
    if (t0 < 64) {
        B1g[t0] = (t0 < 32) ? 0.0f : l1_bg_bl[t0 - 32];
        B2g[t0] = (t0 < 32) ? 0.0f : l2_bg_bl[t0 - 32];
    }
    // Fused head: bus We (32x4) + be(4); gen We (32x2) + be(2)
    if (t0 < 128) {
        int k = t0 >> 2, c = t0 & 3;
        float s = 0.0f;
        for (int m = 0; m < 32; m++) s += lin0_bus_W[k * 32 + m] * linf_bus_W[m * 4 + c];
        WeB[t0] = s;
    }
    if (t0 >= 128 && t0 < 132) {
        int c = t0 - 128;
        float s = linf_bus_b[c];
        for (int m = 0; m < 32; m++) s += lin0_bus_b[m] * linf_bus_W[m * 4 + c];
        beB[c] = s;
    }
    if (t0 >= 132 && t0 < 196) {
        int i = t0 - 132, k = i >> 1, c = i & 1;
        float s = 0.0f;
        for (int m = 0; m < 32; m++) s += lin0_gen_W[k * 32 + m] * linf_gen_W[m * 2 + c];
        WeG[i] = s;
    }
    if (t0 >= 196 && t0 < 198) {
        int c = t0 - 196;
        float s = linf_gen_b[c];
        for (int m = 0; m < 32; m++) s += lin0_gen_b[m] * linf_gen_W[m * 2 + c];
        beG[c] = s;
    }
}

// ---------------------------------------------------------------------------
// Node transform body: bf16 MFMA GEMM [256 x K] @ [K x NOUT] per block.
template <int K, int NOUT, bool RELU_IN>
__device__ __forceinline__ void transform_body(
    int blk, const float* x, int n,
    const unsigned short* __restrict__ Wf, const float* __restrict__ bias,
    unsigned short* __restrict__ y0, unsigned short* __restrict__ y1, float* h,
    char* ldsraw)
{
    constexpr int KT = K / 32, NTN = NOUT / 16, NCH = NOUT / 32;
    constexpr int XS = K + 8;  // shorts
    constexpr int OS = 34;     // floats
    short* lx = (short*)ldsraw;
    float* lo = (float*)ldsraw;

    const int tid = threadIdx.x;
    const int base = blk * 256;
    const int rows = min(256, n - base);
    const int w = tid >> 6, l = tid & 63, quad = l >> 4, ln = l & 15;

    // B fragments + bias
    short8 bf[KT][NTN];
    const short8* wf8 = (const short8*)Wf;
#pragma unroll
    for (int kt = 0; kt < KT; kt++)
#pragma unroll
        for (int nt = 0; nt < NTN; nt++)
            bf[kt][nt] = wf8[(kt * NTN + nt) * 64 + l];
    float bv[NTN];
#pragma unroll
    for (int nt = 0; nt < NTN; nt++) bv[nt] = bias[nt * 16 + ln];

    // ---- stage x tile (fp32 -> bf16, optional relu) ----
    {
        const float4* xg = (const float4*)(x + (size_t)base * K);
        const int T4 = rows * (K / 4);
        for (int q = tid; q < T4; q += 256) {
            float4 v = xg[q];
            if (RELU_IN) {
                v.x = fmaxf(v.x, 0.f); v.y = fmaxf(v.y, 0.f);
                v.z = fmaxf(v.z, 0.f); v.w = fmaxf(v.w, 0.f);
            }
            int r = q / (K / 4), c = (q % (K / 4)) * 4;
            short4 s4;
            s4.x = (short)f2bf(v.x); s4.y = (short)f2bf(v.y);
            s4.z = (short)f2bf(v.z); s4.w = (short)f2bf(v.w);
            *(short4*)&lx[r * XS + c] = s4;
        }
    }
    __syncthreads();

    // ---- MFMA: wave w owns rows [w*64, w*64+64) ----
    floatx4 acc[4][NTN];
#pragma unroll
    for (int mt = 0; mt < 4; mt++)
#pragma unroll
        for (int nt = 0; nt < NTN; nt++) {
            floatx4 c0 = {bv[nt], bv[nt], bv[nt], bv[nt]};
            acc[mt][nt] = c0;
        }
#pragma unroll
    for (int mt = 0; mt < 4; mt++) {
        const int row = w * 64 + mt * 16 + ln;  // A[m = lane&15][k = quad*8+j]
#pragma unroll
        for (int kt = 0; kt < KT; kt++) {
            short8 af = *(const short8*)&lx[row * XS + kt * 32 + quad * 8];
#pragma unroll
            for (int nt = 0; nt < NTN; nt++)
                acc[mt][nt] = __builtin_amdgcn_mfma_f32_16x16x32_bf16(
                    af, bf[kt][nt], acc[mt][nt], 0, 0, 0);
        }
    }

    // ---- epilogue: per-32-col chunk LDS transpose -> coalesced stores ----
    // C/D layout: col = lane&15, row = quad*4 + reg.
#pragma unroll
    for (int c = 0; c < NCH; c++) {
        __syncthreads();
#pragma unroll
        for (int mt = 0; mt < 4; mt++)
#pragma unroll
            for (int d = 0; d < 2; d++) {
                int nt = 2 * c + d;
#pragma unroll
                for (int r = 0; r < 4; r++)
                    lo[(w * 64 + mt * 16 + quad * 4 + r) * OS + d * 16 + ln] = acc[mt][nt][r];
            }
        __syncthreads();
        const int T4 = rows * 8;
        if (c == NCH - 1) {  // h chunk, fp32
            float* og = h + (size_t)base * 32;
            for (int q = tid; q < T4; q += 256) {
                int r = q >> 3, cc = (q & 7) * 4;
                const float* p = &lo[r * OS + cc];
                *(float4*)(og + q * 4) = make_float4(p[0], p[1], p[2], p[3]);
            }
        } else {  // y chunk, bf16
            unsigned short* og = ((c == 0) ? y0 : y1) + (size_t)base * 32;
            for (int q = tid; q < T4; q += 256) {
                int r = q >> 3, cc = (q & 7) * 4;
                const float* p = &lo[r * OS + cc];
                short4 s4;
                s4.x = (short)f2bf(p[0]); s4.y = (short)f2bf(p[1]);
                s4.z = (short)f2bf(p[2]); s4.w = (short)f2bf(p[3]);
                *(short4*)(og + q * 4) = s4;
            }
        }
    }
}

// Layer-1 transform (bus+gen merged).
__global__ __launch_bounds__(256) void tf1_all_kernel(
    const float* xb, const unsigned short* __restrict__ Wfb, const float* __restrict__ Bb,
    unsigned short* __restrict__ yb0, unsigned short* __restrict__ yb1, float* hb,
    const float* xg, const unsigned short* __restrict__ Wfg, const float* __restrict__ Bg,
    unsigned short* __restrict__ yg0, float* hg)
{
    constexpr int XB = 256 * (64 + 8) * 2, OB = 256 * 34 * 4;
    __shared__ __align__(16) char ldsraw[(XB > OB) ? XB : OB];
    int b = blockIdx.x;
    if (b < NB_TF_BUS)
        transform_body<64, 96, false>(b, xb, N_BUS, Wfb, Bb, yb0, yb1, hb, ldsraw);
    else
        transform_body<64, 64, false>(b - NB_TF_BUS, xg, N_GEN, Wfg, Bg, yg0, nullptr, hg, ldsraw);
}

// Layer-2 transform (bus+gen merged).
__global__ __launch_bounds__(256) void tf2_all_kernel(
    const float* xb, const unsigned short* __restrict__ Wfb, const float* __restrict__ Bb,
    unsigned short* __restrict__ yb0, unsigned short* __restrict__ yb1, float* hb,
    const float* xg, const unsigned short* __restrict__ Wfg, const float* __restrict__ Bg,
    unsigned short* __restrict__ yg0, float* hg)
{
    constexpr int XB = 256 * (32 + 8) * 2, OB = 256 * 34 * 4;
    __shared__ __align__(16) char ldsraw[(XB > OB) ? XB : OB];
    int b = blockIdx.x;
    if (b < NB_TF_BUS)
        transform_body<32, 96, true>(b, xb, N_BUS, Wfb, Bb, yb0, yb1, hb, ldsraw);
    else
        transform_body<32, 64, true>(b - NB_TF_BUS, xg, N_GEN, Wfg, Bg, yg0, nullptr, hg, ldsraw);
}

// ---------------------------------------------------------------------------
// Pull body (bf16 y), 4-way pipelined gathers; 8 threads/node.
// rs packed: (row start << 9) | degree  -> ONE load per relation per node.
// FUSE: relu + fused head (We 32xD, be D), write d_out directly.
template <bool FUSE>
__device__ __forceinline__ void pull_body(
    int blk, bool hasB, int n,
    const unsigned* __restrict__ rsA, const unsigned* __restrict__ eA, const unsigned short* __restrict__ yA,
    const unsigned* __restrict__ rsB, const unsigned* __restrict__ eB, const unsigned short* __restrict__ yB,
    float* __restrict__ h,
    const float* __restrict__ We, const float* __restrict__ be, int DOUT, float* __restrict__ outp)
{
    const int tid = threadIdx.x;
    unsigned node = blk * 32u + (tid >> 3);
    int j = (tid & 7) * 4;
    if (node >= (unsigned)n) return;

    float4 r = *(const float4*)(h + (size_t)node * H + j);  // root term

    auto accum_rel = [&](const unsigned* __restrict__ rs, const unsigned* __restrict__ e,
                         const unsigned short* __restrict__ y) {
        unsigned u = rs[node];
        unsigned k0 = u >> 9;
        unsigned c = u & 511u;
        unsigned k1 = k0 + c;
        float4 a0 = make_float4(0.f, 0.f, 0.f, 0.f);
        float4 a1 = make_float4(0.f, 0.f, 0.f, 0.f);
        float4 a2 = make_float4(0.f, 0.f, 0.f, 0.f);
        float4 a3 = make_float4(0.f, 0.f, 0.f, 0.f);
        unsigned k = k0;
        for (; k + 4 <= k1; k += 4) {
            unsigned s0 = e[k], s1 = e[k + 1], s2 = e[k + 2], s3 = e[k + 3];
            ushort4 v0 = *(const ushort4*)(y + (size_t)s0 * H + j);
            ushort4 v1 = *(const ushort4*)(y + (size_t)s1 * H + j);
            ushort4 v2 = *(const ushort4*)(y + (size_t)s2 * H + j);
            ushort4 v3 = *(const ushort4*)(y + (size_t)s3 * H + j);
            a0.x += bf2f(v0.x); a0.y += bf2f(v0.y); a0.z += bf2f(v0.z); a0.w += bf2f(v0.w);
            a1.x += bf2f(v1.x); a1.y += bf2f(v1.y); a1.z += bf2f(v1.z); a1.w += bf2f(v1.w);
            a2.x += bf2f(v2.x); a2.y += bf2f(v2.y); a2.z += bf2f(v2.z); a2.w += bf2f(v2.w);
            a3.x += bf2f(v3.x); a3.y += bf2f(v3.y); a3.z += bf2f(v3.z); a3.w += bf2f(v3.w);
        }
        for (; k < k1; ++k) {
            unsigned s = e[k];
            const ushort4 v = *(const ushort4*)(y + (size_t)s * H + j);
            a0.x += bf2f(v.x); a0.y += bf2f(v.y); a0.z += bf2f(v.z); a0.w += bf2f(v.w);
        }
        a0.x += a1.x + a2.x + a3.x; a0.y += a1.y + a2.y + a3.y;
        a0.z += a1.z + a2.z + a3.z; a0.w += a1.w + a2.w + a3.w;
        float inv = 1.0f / (float)(c > 1u ? c : 1u);
        r.x += a0.x * inv; r.y += a0.y * inv; r.z += a0.z * inv; r.w += a0.w * inv;
    };

    accum_rel(rsA, eA, yA);
    if (hasB) accum_rel(rsB, eB, yB);

    if (!FUSE) {
        *(float4*)(h + (size_t)node * H + j) = r;
        return;
    }

    float p0 = fmaxf(r.x, 0.f), p1 = fmaxf(r.y, 0.f), p2 = fmaxf(r.z, 0.f), p3 = fmaxf(r.w, 0.f);
    float tot[4];
#pragma unroll
    for (int c = 0; c < 4; c++) {
        if (c < DOUT) {
            tot[c] = p0 * We[(j + 0) * DOUT + c] + p1 * We[(j + 1) * DOUT + c]
                   + p2 * We[(j + 2) * DOUT + c] + p3 * We[(j + 3) * DOUT + c];
        } else tot[c] = 0.f;
    }
#pragma unroll
    for (int mask = 1; mask <= 4; mask <<= 1) {
#pragma unroll
        for (int c = 0; c < 4; c++) tot[c] += __shfl_xor(tot[c], mask);
    }
    if ((tid & 7) == 0) {
        if (DOUT == 4) {
            *(float4*)(outp + (size_t)node * 4) =
                make_float4(tot[0] + be[0], tot[1] + be[1], tot[2] + be[2], tot[3] + be[3]);
        } else {
            *(float2*)(outp + (size_t)node * 2) = make_float2(tot[0] + be[0], tot[1] + be[1]);
        }
    }
}

// Merged bus+gen pull launch.
template <bool FUSE>
__global__ __launch_bounds__(256) void pull_all_kernel(
    const unsigned* __restrict__ rsbb, const unsigned* __restrict__ ebb, const unsigned short* __restrict__ ybb,
    const unsigned* __restrict__ rsgb, const unsigned* __restrict__ egb, const unsigned short* __restrict__ ygb,
    float* __restrict__ hb, const float* __restrict__ WeB, const float* __restrict__ beB,
    const unsigned* __restrict__ rsbg, const unsigned* __restrict__ ebg, const unsigned short* __restrict__ ybg,
    float* __restrict__ hg, const float* __restrict__ WeG, const float* __restrict__ beG,
    float* __restrict__ outp)
{
    int b = blockIdx.x;
    if (b < NB_PL_BUS)
        pull_body<FUSE>(b, true, N_BUS, rsbb, ebb, ybb, rsgb, egb, ygb, hb, WeB, beB, 4, outp);
    else
        pull_body<FUSE>(b - NB_PL_BUS, false, N_GEN, rsbg, ebg, ybg, nullptr, nullptr, nullptr,
                        hg, WeG, beG, 2, outp ? outp + (size_t)N_BUS * 4 : nullptr);
}

// ---------------------------------------------------------------------------
extern "C" void kernel_launch(void* const* d_in, const int* in_sizes, int n_in,
                              void* d_out, int out_size, void* d_ws, size_t ws_size,
                              hipStream_t stream) {
    const float* x_bus = (const float*)d_in[0];
    const float* x_gen = (const float*)d_in[1];
    const int* src_bb = (const int*)d_in[2];
    const int* dst_bb = (const int*)d_in[3];
    const int* src_gb = (const int*)d_in[4];
    const int* dst_gb = (const int*)d_in[5];
    const int* src_bg = (const int*)d_in[6];
    const int* dst_bg = (const int*)d_in[7];
    const float* l1_bb_Wl = (const float*)d_in[8];
    const float* l1_bb_bl = (const float*)d_in[9];
    const float* l1_bb_Wr = (const float*)d_in[10];
    const float* l1_gb_Wl = (const float*)d_in[11];
    const float* l1_gb_bl = (const float*)d_in[12];
    const float* l1_gb_Wr = (const float*)d_in[13];
    const float* l1_bg_Wl = (const float*)d_in[14];
    const float* l1_bg_bl = (const float*)d_in[15];
    const float* l1_bg_Wr = (const float*)d_in[16];
    const float* l2_bb_Wl = (const float*)d_in[17];
    const float* l2_bb_bl = (const float*)d_in[18];
    const float* l2_bb_Wr = (const float*)d_in[19];
    const float* l2_gb_Wl = (const float*)d_in[20];
    const float* l2_gb_bl = (const float*)d_in[21];
    const float* l2_gb_Wr = (const float*)d_in[22];
    const float* l2_bg_Wl = (const float*)d_in[23];
    const float* l2_bg_bl = (const float*)d_in[24];
    const float* l2_bg_Wr = (const float*)d_in[25];
    const float* lin0_bus_W = (const float*)d_in[26];
    const float* lin0_bus_b = (const float*)d_in[27];
    const float* linf_bus_W = (const float*)d_in[28];
    const float* linf_bus_b = (const float*)d_in[29];
    const float* lin0_gen_W = (const float*)d_in[30];
    const float* lin0_gen_b = (const float*)d_in[31];
    const float* linf_gen_W = (const float*)d_in[32];
    const float* linf_gen_b = (const float*)d_in[33];

    // Workspace layout (~96 MB).
    char* ws = (char*)d_ws;
    size_t off = 0;
    auto alloc = [&](size_t bytes) {
        char* p = ws + off;
        off += (bytes + 255) & ~(size_t)255;
        return p;
    };
    unsigned* rs_bb = (unsigned*)alloc((size_t)N_BUS * 4);
    unsigned* rs_gb = (unsigned*)alloc((size_t)N_BUS * 4);
    unsigned* rs_bg = (unsigned*)alloc((size_t)N_GEN * 4);
    unsigned* cur_bb = (unsigned*)alloc(NBINS * 4);   // three cursor arrays contiguous
    unsigned* cur_gb = (unsigned*)alloc(NBINS * 4);
    unsigned* cur_bg = (unsigned*)alloc(NBINS * 4);
    unsigned* e_bb = (unsigned*)alloc((size_t)NBK_BUS * CAP_BB * 4);
    unsigned* e_gb = (unsigned*)alloc((size_t)NBK_BUS * CAP_GB * 4);
    unsigned* e_bg = (unsigned*)alloc((size_t)NBK_GEN * CAP_BG * 4);
    unsigned* p_bb = (unsigned*)alloc((size_t)NBK_BUS * CAP_BB * 4);
    unsigned* p_gb = (unsigned*)alloc((size_t)NBK_BUS * CAP_GB * 4);
    unsigned* p_bg = (unsigned*)alloc((size_t)NBK_GEN * CAP_BG * 4);
    unsigned short* y_bb = (unsigned short*)alloc((size_t)N_BUS * H * 2);  // bf16
    unsigned short* y_bg = (unsigned short*)alloc((size_t)N_BUS * H * 2);  // bf16
    unsigned short* y_gb = (unsigned short*)alloc((size_t)N_GEN * H * 2);  // bf16
    float* h_bus = (float*)alloc((size_t)N_BUS * H * 4);
    float* h_gen = (float*)alloc((size_t)N_GEN * H * 4);
    unsigned short* Wf1b = (unsigned short*)alloc(2 * 6 * 64 * 8 * 2);
    float* B1b = (float*)alloc(96 * 4);
    unsigned short* Wf1g = (unsigned short*)alloc(2 * 4 * 64 * 8 * 2);
    float* B1g = (float*)alloc(64 * 4);
    unsigned short* Wf2b = (unsigned short*)alloc(6 * 64 * 8 * 2);
    float* B2b = (float*)alloc(96 * 4);
    unsigned short* Wf2g = (unsigned short*)alloc(4 * 64 * 8 * 2);
    float* B2g = (float*)alloc(64 * 4);
    float* WeB = (float*)alloc(128 * 4);
    float* beB = (float*)alloc(4 * 4);
    float* WeG = (float*)alloc(64 * 4);
    float* beG = (float*)alloc(2 * 4);

    // P0: weights -> MFMA fragment order + fused head + cursor zeroing.
    prep_kernel<<<32, 256, 0, stream>>>(
        l1_bb_Wl, l1_bb_bl, l1_bb_Wr, l1_gb_Wl, l1_gb_bl, l1_gb_Wr,
        l1_bg_Wl, l1_bg_bl, l1_bg_Wr, l2_bb_Wl, l2_bb_bl, l2_bb_Wr,
        l2_gb_Wl, l2_gb_bl, l2_gb_Wr, l2_bg_Wl, l2_bg_bl, l2_bg_Wr,
        lin0_bus_W, lin0_bus_b, linf_bus_W, linf_bus_b,
        lin0_gen_W, lin0_gen_b, linf_gen_W, linf_gen_b,
        Wf1b, B1b, Wf1g, B1g, Wf2b, B2b, Wf2g, B2g, WeB, beB, WeG, beG,
        cur_bb);

    // P1: fixed-capacity bucket partition (no histogram/scan needed).
    part_all_kernel<<<NB_PART_ALL, 256, 0, stream>>>(
        src_bb, dst_bb, cur_bb, p_bb, src_gb, dst_gb, cur_gb, p_gb, src_bg, dst_bg, cur_bg, p_bg);

    // P2: fine CSR (packed rs).
    fine_all_kernel<<<2 * NBK_BUS + NBK_GEN, 256, 0, stream>>>(
        cur_bb, p_bb, rs_bb, e_bb, cur_gb, p_gb, rs_gb, e_gb, cur_bg, p_bg, rs_bg, e_bg);

    // P3: layer-1 transforms.
    tf1_all_kernel<<<NB_TF_BUS + NB_TF_GEN, 256, 0, stream>>>(
        x_bus, Wf1b, B1b, y_bb, y_bg, h_bus, x_gen, Wf1g, B1g, y_gb, h_gen);

    // P4: layer-1 pull.
    pull_all_kernel<false><<<NB_PL_BUS + NB_PL_GEN, 256, 0, stream>>>(
        rs_bb, e_bb, y_bb, rs_gb, e_gb, y_gb, h_bus, WeB, beB,
        rs_bg, e_bg, y_bg, h_gen, WeG, beG, nullptr);

    // P5: layer-2 transforms (relu on staging; h in-place).
    tf2_all_kernel<<<NB_TF_BUS + NB_TF_GEN, 256, 0, stream>>>(
        h_bus, Wf2b, B2b, y_bb, y_bg, h_bus, h_gen, Wf2g, B2g, y_gb, h_gen);

    // P6: layer-2 pull + fused head -> d_out.
    pull_all_kernel<true><<<NB_PL_BUS + NB_PL_GEN, 256, 0, stream>>>(
        rs_bb, e_bb, y_bb, rs_gb, e_gb, y_gb, h_bus, WeB, beB,
        rs_bg, e_bg, y_bg, h_gen, WeG, beG, (float*)d_out);
}